// Round 10
// baseline (339.947 us; speedup 1.0000x reference)
//
#include <hip/hip_runtime.h>
#include <hip/hip_fp16.h>

// GCN, N=50000 nodes, E=800000 edges, 128->128(relu)->64, fp32 accum.
// CSR entries are 2B (src only; norm recomputed as dis[src]*dis[v]).
// Degree-sorted node scheduling: counting-sort perm by degree so nodes
// sharing a wave/block have equal degree (no lockstep-loop waste, no
// block-barrier stall in the fused kernel).
// Layer 1: fp16 MFMA GEMM (x@W1 -> H1 fp16).
// Fused: agg(H1)+b1+relu (16 perm-nodes/block) -> LDS fp16 -> MFMA @ W2^T -> H2.
// Layer 2 agg: gather H2 (perm order), +b2 -> out.

#define Nn 50000
#define Ne 800000
#define SCAN_B ((Nn + 1023) / 1024)   // 49 blocks
#define NBUCK 512

using f16x8 = _Float16 __attribute__((ext_vector_type(8)));
using f32x4 = float __attribute__((ext_vector_type(4)));

// ---------------- degree count + within-bucket rank (2 edges/thread) ----------------
__global__ __launch_bounds__(256) void k_count(const int2* __restrict__ col2,
                                               int* __restrict__ degi,
                                               ushort2* __restrict__ rank2) {
  int t = blockIdx.x * 256 + threadIdx.x;
  if (t < Ne / 2) {
    int2 c = col2[t];
    unsigned short r0 = (unsigned short)atomicAdd(&degi[c.x], 1);
    unsigned short r1 = (unsigned short)atomicAdd(&degi[c.y], 1);
    ushort2 rk; rk.x = r0; rk.y = r1;
    rank2[t] = rk;
  }
}

// ---------------- scan phase 1: block-local exclusive scan + dis + degree hist ----------------
__global__ __launch_bounds__(1024) void k_scan1(const int* __restrict__ degi,
                                                int* __restrict__ rowptr,
                                                float* __restrict__ dis,
                                                int* __restrict__ bsum,
                                                int* __restrict__ dhist) {
  __shared__ int wsum[16];
  __shared__ int lh[NBUCK];
  int tid = threadIdx.x;
  int lane = tid & 63, wid = tid >> 6;
  if (tid < NBUCK) lh[tid] = 0;
  __syncthreads();
  int i = blockIdx.x * 1024 + tid;
  int v = (i < Nn) ? degi[i] : 0;
  if (i < Nn) {
    dis[i] = rsqrtf((float)(v + 1));             // self-loop adds 1
    atomicAdd(&lh[v < NBUCK ? v : NBUCK - 1], 1);
  }
  int incl = v;
  #pragma unroll
  for (int off = 1; off < 64; off <<= 1) {
    int t = __shfl_up(incl, off);
    if (lane >= off) incl += t;
  }
  if (lane == 63) wsum[wid] = incl;
  __syncthreads();
  if (wid == 0) {
    int wv = (lane < 16) ? wsum[lane] : 0;
    #pragma unroll
    for (int off = 1; off < 16; off <<= 1) {
      int t = __shfl_up(wv, off);
      if (lane >= off) wv += t;
    }
    if (lane < 16) wsum[lane] = wv;  // inclusive over wave totals
  }
  __syncthreads();
  int woff = (wid > 0) ? wsum[wid - 1] : 0;
  if (i < Nn) rowptr[i] = woff + incl - v;       // block-local exclusive
  if (tid == 0) bsum[blockIdx.x] = wsum[15];     // block total
  if (tid < NBUCK && lh[tid]) atomicAdd(&dhist[tid], lh[tid]);
}

// ---------------- scan phase 2+3 fused: each block scans the 49 block sums ----------------
__global__ __launch_bounds__(1024) void k_scan3(int* __restrict__ rowptr,
                                                const int* __restrict__ bsum) {
  __shared__ int off_s;
  int tid = threadIdx.x;
  if (tid < 64) {
    int v = (tid < SCAN_B) ? bsum[tid] : 0;
    int incl = v;
    #pragma unroll
    for (int off = 1; off < 64; off <<= 1) {
      int t = __shfl_up(incl, off);
      if (tid >= off) incl += t;
    }
    if (tid == (int)blockIdx.x) off_s = incl - v;          // exclusive offset
    if (blockIdx.x == 0 && tid == SCAN_B - 1) rowptr[Nn] = incl;  // == Ne
  }
  __syncthreads();
  int i = blockIdx.x * 1024 + tid;
  if (i < Nn) rowptr[i] += off_s;
}

// ---------------- exclusive scan of 512-bucket degree histogram ----------------
__global__ __launch_bounds__(512) void k_dscan(const int* __restrict__ dhist,
                                               int* __restrict__ doff) {
  __shared__ int ws[8];
  int tid = threadIdx.x, lane = tid & 63, wid = tid >> 6;
  int v = dhist[tid];
  int incl = v;
  #pragma unroll
  for (int off = 1; off < 64; off <<= 1) {
    int t = __shfl_up(incl, off);
    if (lane >= off) incl += t;
  }
  if (lane == 63) ws[wid] = incl;
  __syncthreads();
  if (wid == 0) {
    int wv = (lane < 8) ? ws[lane] : 0;
    #pragma unroll
    for (int off = 1; off < 8; off <<= 1) {
      int t = __shfl_up(wv, off);
      if (lane >= off) wv += t;
    }
    if (lane < 8) ws[lane] = wv;
  }
  __syncthreads();
  int woff = (wid > 0) ? ws[wid - 1] : 0;
  doff[tid] = woff + incl - v;                   // exclusive
}

// ---------------- counting-sort permutation by degree ----------------
__global__ __launch_bounds__(256) void k_perm(const int* __restrict__ degi,
                                              int* __restrict__ doff,
                                              int* __restrict__ perm) {
  int i = blockIdx.x * 256 + threadIdx.x;
  if (i < Nn) {
    int d = degi[i]; if (d >= NBUCK) d = NBUCK - 1;
    int pos = atomicAdd(&doff[d], 1);
    perm[pos] = i;
  }
}

// ---------------- CSR fill: 2B src only, no atomic (2 edges/thread) ----------------
__global__ __launch_bounds__(256) void k_fill(const int2* __restrict__ row2,
                                              const int2* __restrict__ col2,
                                              const int* __restrict__ rowptr,
                                              const ushort2* __restrict__ rank2,
                                              unsigned short* __restrict__ csr) {
  int t = blockIdx.x * 256 + threadIdx.x;
  if (t >= Ne / 2) return;
  int2 r = row2[t];
  int2 c = col2[t];
  ushort2 k = rank2[t];
  csr[rowptr[c.x] + (int)k.x] = (unsigned short)r.x;
  csr[rowptr[c.y] + (int)k.y] = (unsigned short)r.y;
}

// ---------------- MFMA GEMM: H[n, LDO](fp16) = X[n,128] @ W[128, LDO] ----------------
// A-frag: A[m=lane&15][k=quad*8+j]; B-frag: B[k=quad*8+j][n=lane&15] (W^T in LDS)
// C/D: col=lane&15, row=quad*4+reg (m89-verified)
template <int LDO>
__global__ __launch_bounds__(256) void k_gemm_mfma(const float* __restrict__ X,
                                                   const float* __restrict__ W,
                                                   __half* __restrict__ H, int n) {
  __shared__ _Float16 Xs[64 * 136];        // 64 rows x (128+8 pad)
  __shared__ _Float16 Wts[LDO * 136];      // transposed W
  const int tid = threadIdx.x;
  const int base = blockIdx.x * 64;

  {
    constexpr int C4 = LDO / 4;
    for (int idx4 = tid; idx4 < 32 * LDO; idx4 += 256) {
      int k = idx4 / C4;
      int c = (idx4 % C4) * 4;
      float4 wv = ((const float4*)W)[idx4];
      Wts[(c + 0) * 136 + k] = (_Float16)wv.x;
      Wts[(c + 1) * 136 + k] = (_Float16)wv.y;
      Wts[(c + 2) * 136 + k] = (_Float16)wv.z;
      Wts[(c + 3) * 136 + k] = (_Float16)wv.w;
    }
  }
  {
    for (int u = tid; u < 64 * 16; u += 256) {
      int r = u >> 4, seg = u & 15;
      int node = base + r;
      if (node >= n) node = n - 1;
      const float4* xg = (const float4*)(X + (size_t)node * 128 + seg * 8);
      float4 x0 = xg[0], x1 = xg[1];
      f16x8 hv;
      hv[0] = (_Float16)x0.x; hv[1] = (_Float16)x0.y;
      hv[2] = (_Float16)x0.z; hv[3] = (_Float16)x0.w;
      hv[4] = (_Float16)x1.x; hv[5] = (_Float16)x1.y;
      hv[6] = (_Float16)x1.z; hv[7] = (_Float16)x1.w;
      *(f16x8*)&Xs[r * 136 + seg * 8] = hv;
    }
  }
  __syncthreads();

  const int w = tid >> 6, lane = tid & 63;
  const int quad = lane >> 4, mrow = lane & 15;
  constexpr int NCT = LDO / 16;

  f32x4 acc[NCT];
  #pragma unroll
  for (int ct = 0; ct < NCT; ++ct) acc[ct] = (f32x4){0.f, 0.f, 0.f, 0.f};

  #pragma unroll
  for (int ko = 0; ko < 4; ++ko) {
    f16x8 av = *(const f16x8*)&Xs[(w * 16 + mrow) * 136 + ko * 32 + quad * 8];
    #pragma unroll
    for (int ct = 0; ct < NCT; ++ct) {
      f16x8 bv = *(const f16x8*)&Wts[(ct * 16 + mrow) * 136 + ko * 32 + quad * 8];
      acc[ct] = __builtin_amdgcn_mfma_f32_16x16x32_f16(av, bv, acc[ct], 0, 0, 0);
    }
  }

  #pragma unroll
  for (int ct = 0; ct < NCT; ++ct) {
    #pragma unroll
    for (int r = 0; r < 4; ++r) {
      int node = base + w * 16 + quad * 4 + r;
      if (node < n)
        H[(size_t)node * LDO + ct * 16 + mrow] = __float2half(acc[ct][r]);
    }
  }
}

__device__ __forceinline__ float2 h2f(unsigned int u) {
  return __half22float2(*(const __half2*)&u);
}

// ---------------- FUSED: agg128(+b1, relu) -> LDS fp16 -> MFMA @ W2 -> H2 fp16 ----------------
// Nodes taken in degree-sorted perm order: the block's 16 nodes have ~equal
// degree, so the pre-MFMA barrier causes no straggler stall.
__global__ __launch_bounds__(256) void k_agg128_gemm64(
    const __half* __restrict__ H, const unsigned short* __restrict__ csr,
    const int* __restrict__ rowptr, const float* __restrict__ dis,
    const int* __restrict__ perm,
    const float* __restrict__ bias, const float* __restrict__ W2,
    __half* __restrict__ H2, int n) {
  __shared__ _Float16 Wts[64 * 136];   // W2 transposed: [c][k]
  __shared__ _Float16 Hs[16 * 136];    // block's 16 aggregated rows (fp16)
  __shared__ int spv[16];              // block's real node ids

  const int tid = threadIdx.x;
  const int wid = tid >> 6, lane = tid & 63;
  const int sub = lane >> 4, fl = lane & 15;
  const int nb = wid * 4 + sub;                  // node-in-block [0,16)
  const int v = perm[blockIdx.x * 16 + nb];      // Nn = 3125*16 exact
  if (fl == 0) spv[nb] = v;

  // stage W2^T (fp32 [128][64] -> fp16 Wts[c][k]); 2048 float4, 8/thread
  for (int idx4 = tid; idx4 < 2048; idx4 += 256) {
    int k = idx4 >> 4;
    int c = (idx4 & 15) * 4;
    float4 wv = ((const float4*)W2)[idx4];
    Wts[(c + 0) * 136 + k] = (_Float16)wv.x;
    Wts[(c + 1) * 136 + k] = (_Float16)wv.y;
    Wts[(c + 2) * 136 + k] = (_Float16)wv.z;
    Wts[(c + 3) * 136 + k] = (_Float16)wv.w;
  }

  // ---- stage A: aggregate node v's 8 feats per lane ----
  int s = rowptr[v], e = rowptr[v + 1];
  float d = dis[v];
  float sw = d * d;                              // self-loop norm = 1/deg
  const uint4* Hq = (const uint4*)H;             // 16 uint4 per 256B row
  uint4 hv = Hq[(size_t)v * 16 + fl];
  float2 p0 = h2f(hv.x), p1 = h2f(hv.y), p2 = h2f(hv.z), p3 = h2f(hv.w);
  float a0 = p0.x * sw, a1 = p0.y * sw, a2 = p1.x * sw, a3 = p1.y * sw;
  float a4 = p2.x * sw, a5 = p2.y * sw, a6 = p3.x * sw, a7 = p3.y * sw;
  constexpr int D = 6;
  int i = s;
  for (; i + D <= e; i += D) {
    int srcs[D];
    uint4 q[D];
    float wd[D];
    #pragma unroll
    for (int j = 0; j < D; ++j) srcs[j] = csr[i + j];
    #pragma unroll
    for (int j = 0; j < D; ++j) q[j] = Hq[(size_t)srcs[j] * 16 + fl];
    #pragma unroll
    for (int j = 0; j < D; ++j) wd[j] = dis[srcs[j]];
    #pragma unroll
    for (int j = 0; j < D; ++j) {
      float w = wd[j] * d;
      float2 t;
      t = h2f(q[j].x); a0 = fmaf(w, t.x, a0); a1 = fmaf(w, t.y, a1);
      t = h2f(q[j].y); a2 = fmaf(w, t.x, a2); a3 = fmaf(w, t.y, a3);
      t = h2f(q[j].z); a4 = fmaf(w, t.x, a4); a5 = fmaf(w, t.y, a5);
      t = h2f(q[j].w); a6 = fmaf(w, t.x, a6); a7 = fmaf(w, t.y, a7);
    }
  }
  if (i < e) {                                   // masked tail batch
    int srcs[D];
    uint4 q[D];
    float wd[D];
    #pragma unroll
    for (int j = 0; j < D; ++j) {
      int idx = (i + j < e) ? i + j : e - 1;
      srcs[j] = csr[idx];
    }
    #pragma unroll
    for (int j = 0; j < D; ++j) q[j] = Hq[(size_t)srcs[j] * 16 + fl];
    #pragma unroll
    for (int j = 0; j < D; ++j) wd[j] = dis[srcs[j]];
    #pragma unroll
    for (int j = 0; j < D; ++j) {
      float w = (i + j < e) ? wd[j] * d : 0.f;
      float2 t;
      t = h2f(q[j].x); a0 = fmaf(w, t.x, a0); a1 = fmaf(w, t.y, a1);
      t = h2f(q[j].y); a2 = fmaf(w, t.x, a2); a3 = fmaf(w, t.y, a3);
      t = h2f(q[j].z); a4 = fmaf(w, t.x, a4); a5 = fmaf(w, t.y, a5);
      t = h2f(q[j].w); a6 = fmaf(w, t.x, a6); a7 = fmaf(w, t.y, a7);
    }
  }
  // +b1, relu, fp16 -> LDS row nb
  {
    const float4* Bq = (const float4*)bias;
    float4 b0 = Bq[fl * 2], b1v = Bq[fl * 2 + 1];
    f16x8 hrow;
    hrow[0] = (_Float16)fmaxf(a0 + b0.x, 0.f);
    hrow[1] = (_Float16)fmaxf(a1 + b0.y, 0.f);
    hrow[2] = (_Float16)fmaxf(a2 + b0.z, 0.f);
    hrow[3] = (_Float16)fmaxf(a3 + b0.w, 0.f);
    hrow[4] = (_Float16)fmaxf(a4 + b1v.x, 0.f);
    hrow[5] = (_Float16)fmaxf(a5 + b1v.y, 0.f);
    hrow[6] = (_Float16)fmaxf(a6 + b1v.z, 0.f);
    hrow[7] = (_Float16)fmaxf(a7 + b1v.w, 0.f);
    *(f16x8*)&Hs[nb * 136 + fl * 8] = hrow;
  }
  __syncthreads();

  // ---- stage B: 16x64 = (16x128) @ (128x64), wave w -> cols [w*16, w*16+16) ----
  const int quad = lane >> 4, mrow = lane & 15;
  f32x4 acc = (f32x4){0.f, 0.f, 0.f, 0.f};
  #pragma unroll
  for (int ko = 0; ko < 4; ++ko) {
    f16x8 av = *(const f16x8*)&Hs[mrow * 136 + ko * 32 + quad * 8];
    f16x8 bv = *(const f16x8*)&Wts[(wid * 16 + mrow) * 136 + ko * 32 + quad * 8];
    acc = __builtin_amdgcn_mfma_f32_16x16x32_f16(av, bv, acc, 0, 0, 0);
  }
  #pragma unroll
  for (int r = 0; r < 4; ++r) {
    int node = spv[quad * 4 + r];
    H2[(size_t)node * 64 + wid * 16 + mrow] = __float2half(acc[r]);
  }
}

// ---------------- aggregate 64 feats (+bias, no relu), perm order ----------------
// 4 nodes/wave, 16 lanes/node, uint2 (4 feats) per lane; depth-8 batches.
__global__ __launch_bounds__(256) void k_agg64(const __half* __restrict__ H,
                                               const unsigned short* __restrict__ csr,
                                               const int* __restrict__ rowptr,
                                               const float* __restrict__ dis,
                                               const int* __restrict__ perm,
                                               const float* __restrict__ bias,
                                               float* __restrict__ Out, int n) {
  const int wid = threadIdx.x >> 6, lane = threadIdx.x & 63;
  const int sub = lane >> 4, fl = lane & 15;
  int v = perm[blockIdx.x * 16 + wid * 4 + sub];
  int s = rowptr[v], e = rowptr[v + 1];
  float d = dis[v];
  float sw = d * d;
  const uint2* Hq = (const uint2*)H;             // 16 uint2 per 128B row
  uint2 hv = Hq[(size_t)v * 16 + fl];
  float2 p0 = h2f(hv.x), p1 = h2f(hv.y);
  float a0 = p0.x * sw, a1 = p0.y * sw, a2 = p1.x * sw, a3 = p1.y * sw;
  constexpr int D = 8;
  int i = s;
  for (; i + D <= e; i += D) {
    int srcs[D];
    uint2 q[D];
    float wd[D];
    #pragma unroll
    for (int j = 0; j < D; ++j) srcs[j] = csr[i + j];
    #pragma unroll
    for (int j = 0; j < D; ++j) q[j] = Hq[(size_t)srcs[j] * 16 + fl];
    #pragma unroll
    for (int j = 0; j < D; ++j) wd[j] = dis[srcs[j]];
    #pragma unroll
    for (int j = 0; j < D; ++j) {
      float w = wd[j] * d;
      float2 t;
      t = h2f(q[j].x); a0 = fmaf(w, t.x, a0); a1 = fmaf(w, t.y, a1);
      t = h2f(q[j].y); a2 = fmaf(w, t.x, a2); a3 = fmaf(w, t.y, a3);
    }
  }
  if (i < e) {                                   // masked tail batch
    int srcs[D];
    uint2 q[D];
    float wd[D];
    #pragma unroll
    for (int j = 0; j < D; ++j) {
      int idx = (i + j < e) ? i + j : e - 1;
      srcs[j] = csr[idx];
    }
    #pragma unroll
    for (int j = 0; j < D; ++j) q[j] = Hq[(size_t)srcs[j] * 16 + fl];
    #pragma unroll
    for (int j = 0; j < D; ++j) wd[j] = dis[srcs[j]];
    #pragma unroll
    for (int j = 0; j < D; ++j) {
      float w = (i + j < e) ? wd[j] * d : 0.f;
      float2 t;
      t = h2f(q[j].x); a0 = fmaf(w, t.x, a0); a1 = fmaf(w, t.y, a1);
      t = h2f(q[j].y); a2 = fmaf(w, t.x, a2); a3 = fmaf(w, t.y, a3);
    }
  }
  const float4* Bq = (const float4*)bias;
  float4 b = Bq[fl];
  float4 o = make_float4(a0 + b.x, a1 + b.y, a2 + b.z, a3 + b.w);
  ((float4*)(Out + (size_t)v * 64))[fl] = o;
}

extern "C" void kernel_launch(void* const* d_in, const int* in_sizes, int n_in,
                              void* d_out, int out_size, void* d_ws, size_t ws_size,
                              hipStream_t stream) {
  const float* x  = (const float*)d_in[0];
  const int*   ei = (const int*)d_in[1];    // [2, E] row-major
  const int*   row = ei;                    // edge_index[0] (source)
  const int*   col = ei + Ne;               // edge_index[1] (dest / segment)
  const float* W1 = (const float*)d_in[2];
  const float* b1 = (const float*)d_in[3];
  const float* W2 = (const float*)d_in[4];
  const float* b2 = (const float*)d_in[5];
  float* out = (float*)d_out;

  char* ws = (char*)d_ws;
  size_t off = 0;
  auto alloc = [&](size_t bytes) -> void* {
    void* p = ws + off;
    off += (bytes + 255) & ~(size_t)255;
    return p;
  };
  int*    degi   = (int*)   alloc(Nn * sizeof(int));       // zeroed
  int*    dhist  = (int*)   alloc(NBUCK * sizeof(int));    // zeroed (adjacent)
  int*    doff   = (int*)   alloc(NBUCK * sizeof(int));
  int*    rowptr = (int*)   alloc((Nn + 1) * sizeof(int));
  float*  dis    = (float*) alloc(Nn * sizeof(float));
  int*    bsum   = (int*)   alloc(64 * sizeof(int));
  int*    perm   = (int*)   alloc(Nn * sizeof(int));
  unsigned short* rank = (unsigned short*)alloc((size_t)Ne * sizeof(unsigned short)); // 1.6 MB
  unsigned short* csr  = (unsigned short*)alloc((size_t)Ne * sizeof(unsigned short)); // 1.6 MB
  __half* H1     = (__half*)alloc((size_t)Nn * 128 * sizeof(__half));  // 12.8 MB
  __half* H2     = (__half*)alloc((size_t)Nn * 64 * sizeof(__half));   // 6.4 MB

  // degi (padded to 256) and dhist are adjacent: one memset covers both
  hipMemsetAsync(degi, 0, ((Nn * sizeof(int) + 255) & ~(size_t)255) + NBUCK * sizeof(int), stream);

  const int E2B = (Ne / 2 + 255) / 256;     // 1563 (2 edges/thread)
  const int NGB = (Nn + 15) / 16;           // 3125 node groups (16 nodes each)
  const int GT  = (Nn + 63) / 64;           // 782 node tiles (gemm)

  k_count<<<E2B, 256, 0, stream>>>((const int2*)col, degi, (ushort2*)rank);
  k_scan1<<<SCAN_B, 1024, 0, stream>>>(degi, rowptr, dis, bsum, dhist);
  k_scan3<<<SCAN_B, 1024, 0, stream>>>(rowptr, bsum);
  k_dscan<<<1, 512, 0, stream>>>(dhist, doff);
  k_perm<<<(Nn + 255) / 256, 256, 0, stream>>>(degi, doff, perm);
  k_fill<<<E2B, 256, 0, stream>>>((const int2*)row, (const int2*)col, rowptr,
                                  (const ushort2*)rank, csr);

  // layer 1 GEMM: H1 = fp16(x @ W1)
  k_gemm_mfma<128><<<GT, 256, 0, stream>>>(x, W1, H1, Nn);
  // fused: H2 = fp16( relu(agg(H1) + b1) @ W2 ), degree-sorted blocks
  k_agg128_gemm64<<<NGB, 256, 0, stream>>>(H1, csr, rowptr, dis, perm, b1, W2, H2, Nn);
  // layer 2 agg: out = agg(H2) + b2, degree-sorted waves
  k_agg64<<<NGB, 256, 0, stream>>>(H2, csr, rowptr, dis, perm, b2, out, Nn);
}

// Round 11
// 205.417 us; speedup vs baseline: 1.6549x; 1.6549x over previous
//
#include <hip/hip_runtime.h>
#include <hip/hip_fp16.h>

// GCN, N=50000 nodes, E=800000 edges, 128->128(relu)->64, fp32 accum.
// CSR entries are 2B (src only; norm recomputed as dis[src]*dis[v]).
// k_count emits per-edge bucket rank (no atomic in fill); 2 edges/thread.
// Layer 1: fp16 MFMA GEMM (x@W1 -> H1 fp16).
// Fused: agg(H1)+b1+relu (16 nodes/block) -> LDS fp16 -> MFMA @ W2^T -> H2.
// Layer 2 agg: gather H2, +b2 -> out.
// NOTE (r10 post-mortem): degree-sorted scheduling bought ~0 and its
// counting-sort perm cost 133 us (30 hot atomic addresses serialize).
// Agg kernels sit at the random-gather service floor; natural order kept.

#define Nn 50000
#define Ne 800000
#define SCAN_B ((Nn + 1023) / 1024)   // 49 blocks

using f16x8 = _Float16 __attribute__((ext_vector_type(8)));
using f32x4 = float __attribute__((ext_vector_type(4)));

// ---------------- degree count + within-bucket rank (2 edges/thread) ----------------
__global__ __launch_bounds__(256) void k_count(const int2* __restrict__ col2,
                                               int* __restrict__ degi,
                                               ushort2* __restrict__ rank2) {
  int t = blockIdx.x * 256 + threadIdx.x;
  if (t < Ne / 2) {
    int2 c = col2[t];
    unsigned short r0 = (unsigned short)atomicAdd(&degi[c.x], 1);
    unsigned short r1 = (unsigned short)atomicAdd(&degi[c.y], 1);
    ushort2 rk; rk.x = r0; rk.y = r1;
    rank2[t] = rk;
  }
}

// ---------------- scan phase 1: block-local exclusive scan + dis ----------------
__global__ __launch_bounds__(1024) void k_scan1(const int* __restrict__ degi,
                                                int* __restrict__ rowptr,
                                                float* __restrict__ dis,
                                                int* __restrict__ bsum) {
  __shared__ int wsum[16];
  int tid = threadIdx.x;
  int lane = tid & 63, wid = tid >> 6;
  int i = blockIdx.x * 1024 + tid;
  int v = (i < Nn) ? degi[i] : 0;
  if (i < Nn) dis[i] = rsqrtf((float)(v + 1));   // self-loop adds 1
  int incl = v;
  #pragma unroll
  for (int off = 1; off < 64; off <<= 1) {
    int t = __shfl_up(incl, off);
    if (lane >= off) incl += t;
  }
  if (lane == 63) wsum[wid] = incl;
  __syncthreads();
  if (wid == 0) {
    int wv = (lane < 16) ? wsum[lane] : 0;
    #pragma unroll
    for (int off = 1; off < 16; off <<= 1) {
      int t = __shfl_up(wv, off);
      if (lane >= off) wv += t;
    }
    if (lane < 16) wsum[lane] = wv;  // inclusive over wave totals
  }
  __syncthreads();
  int woff = (wid > 0) ? wsum[wid - 1] : 0;
  if (i < Nn) rowptr[i] = woff + incl - v;       // block-local exclusive
  if (tid == 0) bsum[blockIdx.x] = wsum[15];     // block total
}

// ---------------- scan phase 2+3 fused: each block scans the 49 block sums ----------------
__global__ __launch_bounds__(1024) void k_scan3(int* __restrict__ rowptr,
                                                const int* __restrict__ bsum) {
  __shared__ int off_s;
  int tid = threadIdx.x;
  if (tid < 64) {
    int v = (tid < SCAN_B) ? bsum[tid] : 0;
    int incl = v;
    #pragma unroll
    for (int off = 1; off < 64; off <<= 1) {
      int t = __shfl_up(incl, off);
      if (tid >= off) incl += t;
    }
    if (tid == (int)blockIdx.x) off_s = incl - v;          // exclusive offset
    if (blockIdx.x == 0 && tid == SCAN_B - 1) rowptr[Nn] = incl;  // == Ne
  }
  __syncthreads();
  int i = blockIdx.x * 1024 + tid;
  if (i < Nn) rowptr[i] += off_s;
}

// ---------------- CSR fill: 2B src only, no atomic (2 edges/thread) ----------------
__global__ __launch_bounds__(256) void k_fill(const int2* __restrict__ row2,
                                              const int2* __restrict__ col2,
                                              const int* __restrict__ rowptr,
                                              const ushort2* __restrict__ rank2,
                                              unsigned short* __restrict__ csr) {
  int t = blockIdx.x * 256 + threadIdx.x;
  if (t >= Ne / 2) return;
  int2 r = row2[t];
  int2 c = col2[t];
  ushort2 k = rank2[t];
  csr[rowptr[c.x] + (int)k.x] = (unsigned short)r.x;
  csr[rowptr[c.y] + (int)k.y] = (unsigned short)r.y;
}

// ---------------- MFMA GEMM: H[n, LDO](fp16) = X[n,128] @ W[128, LDO] ----------------
// A-frag: A[m=lane&15][k=quad*8+j]; B-frag: B[k=quad*8+j][n=lane&15] (W^T in LDS)
// C/D: col=lane&15, row=quad*4+reg (m89-verified)
template <int LDO>
__global__ __launch_bounds__(256) void k_gemm_mfma(const float* __restrict__ X,
                                                   const float* __restrict__ W,
                                                   __half* __restrict__ H, int n) {
  __shared__ _Float16 Xs[64 * 136];        // 64 rows x (128+8 pad)
  __shared__ _Float16 Wts[LDO * 136];      // transposed W
  const int tid = threadIdx.x;
  const int base = blockIdx.x * 64;

  {
    constexpr int C4 = LDO / 4;
    for (int idx4 = tid; idx4 < 32 * LDO; idx4 += 256) {
      int k = idx4 / C4;
      int c = (idx4 % C4) * 4;
      float4 wv = ((const float4*)W)[idx4];
      Wts[(c + 0) * 136 + k] = (_Float16)wv.x;
      Wts[(c + 1) * 136 + k] = (_Float16)wv.y;
      Wts[(c + 2) * 136 + k] = (_Float16)wv.z;
      Wts[(c + 3) * 136 + k] = (_Float16)wv.w;
    }
  }
  {
    for (int u = tid; u < 64 * 16; u += 256) {
      int r = u >> 4, seg = u & 15;
      int node = base + r;
      if (node >= n) node = n - 1;
      const float4* xg = (const float4*)(X + (size_t)node * 128 + seg * 8);
      float4 x0 = xg[0], x1 = xg[1];
      f16x8 hv;
      hv[0] = (_Float16)x0.x; hv[1] = (_Float16)x0.y;
      hv[2] = (_Float16)x0.z; hv[3] = (_Float16)x0.w;
      hv[4] = (_Float16)x1.x; hv[5] = (_Float16)x1.y;
      hv[6] = (_Float16)x1.z; hv[7] = (_Float16)x1.w;
      *(f16x8*)&Xs[r * 136 + seg * 8] = hv;
    }
  }
  __syncthreads();

  const int w = tid >> 6, lane = tid & 63;
  const int quad = lane >> 4, mrow = lane & 15;
  constexpr int NCT = LDO / 16;

  f32x4 acc[NCT];
  #pragma unroll
  for (int ct = 0; ct < NCT; ++ct) acc[ct] = (f32x4){0.f, 0.f, 0.f, 0.f};

  #pragma unroll
  for (int ko = 0; ko < 4; ++ko) {
    f16x8 av = *(const f16x8*)&Xs[(w * 16 + mrow) * 136 + ko * 32 + quad * 8];
    #pragma unroll
    for (int ct = 0; ct < NCT; ++ct) {
      f16x8 bv = *(const f16x8*)&Wts[(ct * 16 + mrow) * 136 + ko * 32 + quad * 8];
      acc[ct] = __builtin_amdgcn_mfma_f32_16x16x32_f16(av, bv, acc[ct], 0, 0, 0);
    }
  }

  #pragma unroll
  for (int ct = 0; ct < NCT; ++ct) {
    #pragma unroll
    for (int r = 0; r < 4; ++r) {
      int node = base + w * 16 + quad * 4 + r;
      if (node < n)
        H[(size_t)node * LDO + ct * 16 + mrow] = __float2half(acc[ct][r]);
    }
  }
}

__device__ __forceinline__ float2 h2f(unsigned int u) {
  return __half22float2(*(const __half2*)&u);
}

// ---------------- FUSED: agg128(+b1, relu) -> LDS fp16 -> MFMA @ W2 -> H2 fp16 ----------------
// Stage A (agg): 4 nodes/wave, 16 lanes/node, uint4 (8 fp16 feats)/lane,
//   depth-6 edge batches + masked tail => 12 gathers in flight per node.
// Stage B (gemm): block's 16-node x 128 tile -> LDS; wave w computes output
//   col-tile [w*16, w*16+16) via 4x mfma_f32_16x16x32_f16 against W2^T (LDS).
// Nn = 50000 = 3125 * 16 exactly -> no partial blocks.
__global__ __launch_bounds__(256) void k_agg128_gemm64(
    const __half* __restrict__ H, const unsigned short* __restrict__ csr,
    const int* __restrict__ rowptr, const float* __restrict__ dis,
    const float* __restrict__ bias, const float* __restrict__ W2,
    __half* __restrict__ H2, int n) {
  __shared__ _Float16 Wts[64 * 136];   // W2 transposed: [c][k]
  __shared__ _Float16 Hs[16 * 136];    // block's 16 aggregated rows (fp16)

  const int tid = threadIdx.x;
  const int wid = tid >> 6, lane = tid & 63;
  const int sub = lane >> 4, fl = lane & 15;
  const int nb = wid * 4 + sub;                  // node-in-block [0,16)
  const int v = blockIdx.x * 16 + nb;

  // stage W2^T (fp32 [128][64] -> fp16 Wts[c][k]); 2048 float4, 8/thread
  for (int idx4 = tid; idx4 < 2048; idx4 += 256) {
    int k = idx4 >> 4;
    int c = (idx4 & 15) * 4;
    float4 wv = ((const float4*)W2)[idx4];
    Wts[(c + 0) * 136 + k] = (_Float16)wv.x;
    Wts[(c + 1) * 136 + k] = (_Float16)wv.y;
    Wts[(c + 2) * 136 + k] = (_Float16)wv.z;
    Wts[(c + 3) * 136 + k] = (_Float16)wv.w;
  }

  // ---- stage A: aggregate node v's 8 feats per lane ----
  int s = rowptr[v], e = rowptr[v + 1];
  float d = dis[v];
  float sw = d * d;                              // self-loop norm = 1/deg
  const uint4* Hq = (const uint4*)H;             // 16 uint4 per 256B row
  uint4 hv = Hq[(size_t)v * 16 + fl];
  float2 p0 = h2f(hv.x), p1 = h2f(hv.y), p2 = h2f(hv.z), p3 = h2f(hv.w);
  float a0 = p0.x * sw, a1 = p0.y * sw, a2 = p1.x * sw, a3 = p1.y * sw;
  float a4 = p2.x * sw, a5 = p2.y * sw, a6 = p3.x * sw, a7 = p3.y * sw;
  constexpr int D = 6;
  int i = s;
  for (; i + D <= e; i += D) {
    int srcs[D];
    uint4 q[D];
    float wd[D];
    #pragma unroll
    for (int j = 0; j < D; ++j) srcs[j] = csr[i + j];
    #pragma unroll
    for (int j = 0; j < D; ++j) q[j] = Hq[(size_t)srcs[j] * 16 + fl];
    #pragma unroll
    for (int j = 0; j < D; ++j) wd[j] = dis[srcs[j]];
    #pragma unroll
    for (int j = 0; j < D; ++j) {
      float w = wd[j] * d;
      float2 t;
      t = h2f(q[j].x); a0 = fmaf(w, t.x, a0); a1 = fmaf(w, t.y, a1);
      t = h2f(q[j].y); a2 = fmaf(w, t.x, a2); a3 = fmaf(w, t.y, a3);
      t = h2f(q[j].z); a4 = fmaf(w, t.x, a4); a5 = fmaf(w, t.y, a5);
      t = h2f(q[j].w); a6 = fmaf(w, t.x, a6); a7 = fmaf(w, t.y, a7);
    }
  }
  if (i < e) {                                   // masked tail batch
    int srcs[D];
    uint4 q[D];
    float wd[D];
    #pragma unroll
    for (int j = 0; j < D; ++j) {
      int idx = (i + j < e) ? i + j : e - 1;
      srcs[j] = csr[idx];
    }
    #pragma unroll
    for (int j = 0; j < D; ++j) q[j] = Hq[(size_t)srcs[j] * 16 + fl];
    #pragma unroll
    for (int j = 0; j < D; ++j) wd[j] = dis[srcs[j]];
    #pragma unroll
    for (int j = 0; j < D; ++j) {
      float w = (i + j < e) ? wd[j] * d : 0.f;
      float2 t;
      t = h2f(q[j].x); a0 = fmaf(w, t.x, a0); a1 = fmaf(w, t.y, a1);
      t = h2f(q[j].y); a2 = fmaf(w, t.x, a2); a3 = fmaf(w, t.y, a3);
      t = h2f(q[j].z); a4 = fmaf(w, t.x, a4); a5 = fmaf(w, t.y, a5);
      t = h2f(q[j].w); a6 = fmaf(w, t.x, a6); a7 = fmaf(w, t.y, a7);
    }
  }
  // +b1, relu, fp16 -> LDS row nb
  {
    const float4* Bq = (const float4*)bias;
    float4 b0 = Bq[fl * 2], b1v = Bq[fl * 2 + 1];
    f16x8 hrow;
    hrow[0] = (_Float16)fmaxf(a0 + b0.x, 0.f);
    hrow[1] = (_Float16)fmaxf(a1 + b0.y, 0.f);
    hrow[2] = (_Float16)fmaxf(a2 + b0.z, 0.f);
    hrow[3] = (_Float16)fmaxf(a3 + b0.w, 0.f);
    hrow[4] = (_Float16)fmaxf(a4 + b1v.x, 0.f);
    hrow[5] = (_Float16)fmaxf(a5 + b1v.y, 0.f);
    hrow[6] = (_Float16)fmaxf(a6 + b1v.z, 0.f);
    hrow[7] = (_Float16)fmaxf(a7 + b1v.w, 0.f);
    *(f16x8*)&Hs[nb * 136 + fl * 8] = hrow;
  }
  __syncthreads();

  // ---- stage B: 16x64 = (16x128) @ (128x64), wave w -> cols [w*16, w*16+16) ----
  const int quad = lane >> 4, mrow = lane & 15;
  f32x4 acc = (f32x4){0.f, 0.f, 0.f, 0.f};
  #pragma unroll
  for (int ko = 0; ko < 4; ++ko) {
    f16x8 av = *(const f16x8*)&Hs[mrow * 136 + ko * 32 + quad * 8];
    f16x8 bv = *(const f16x8*)&Wts[(wid * 16 + mrow) * 136 + ko * 32 + quad * 8];
    acc = __builtin_amdgcn_mfma_f32_16x16x32_f16(av, bv, acc, 0, 0, 0);
  }
  #pragma unroll
  for (int r = 0; r < 4; ++r) {
    int node = blockIdx.x * 16 + quad * 4 + r;
    if (node < n)
      H2[(size_t)node * 64 + wid * 16 + mrow] = __float2half(acc[r]);
  }
}

// ---------------- aggregate 64 feats (+bias, no relu) ----------------
// 4 nodes/wave, 16 lanes/node, uint2 (4 feats) per lane; depth-8 batches.
__global__ __launch_bounds__(256) void k_agg64(const __half* __restrict__ H,
                                               const unsigned short* __restrict__ csr,
                                               const int* __restrict__ rowptr,
                                               const float* __restrict__ dis,
                                               const float* __restrict__ bias,
                                               float* __restrict__ Out, int n) {
  const int wid = threadIdx.x >> 6, lane = threadIdx.x & 63;
  const int sub = lane >> 4, fl = lane & 15;
  int v = blockIdx.x * 16 + wid * 4 + sub;
  if (v >= n) return;
  int s = rowptr[v], e = rowptr[v + 1];
  float d = dis[v];
  float sw = d * d;
  const uint2* Hq = (const uint2*)H;             // 16 uint2 per 128B row
  uint2 hv = Hq[(size_t)v * 16 + fl];
  float2 p0 = h2f(hv.x), p1 = h2f(hv.y);
  float a0 = p0.x * sw, a1 = p0.y * sw, a2 = p1.x * sw, a3 = p1.y * sw;
  constexpr int D = 8;
  int i = s;
  for (; i + D <= e; i += D) {
    int srcs[D];
    uint2 q[D];
    float wd[D];
    #pragma unroll
    for (int j = 0; j < D; ++j) srcs[j] = csr[i + j];
    #pragma unroll
    for (int j = 0; j < D; ++j) q[j] = Hq[(size_t)srcs[j] * 16 + fl];
    #pragma unroll
    for (int j = 0; j < D; ++j) wd[j] = dis[srcs[j]];
    #pragma unroll
    for (int j = 0; j < D; ++j) {
      float w = wd[j] * d;
      float2 t;
      t = h2f(q[j].x); a0 = fmaf(w, t.x, a0); a1 = fmaf(w, t.y, a1);
      t = h2f(q[j].y); a2 = fmaf(w, t.x, a2); a3 = fmaf(w, t.y, a3);
    }
  }
  if (i < e) {                                   // masked tail batch
    int srcs[D];
    uint2 q[D];
    float wd[D];
    #pragma unroll
    for (int j = 0; j < D; ++j) {
      int idx = (i + j < e) ? i + j : e - 1;
      srcs[j] = csr[idx];
    }
    #pragma unroll
    for (int j = 0; j < D; ++j) q[j] = Hq[(size_t)srcs[j] * 16 + fl];
    #pragma unroll
    for (int j = 0; j < D; ++j) wd[j] = dis[srcs[j]];
    #pragma unroll
    for (int j = 0; j < D; ++j) {
      float w = (i + j < e) ? wd[j] * d : 0.f;
      float2 t;
      t = h2f(q[j].x); a0 = fmaf(w, t.x, a0); a1 = fmaf(w, t.y, a1);
      t = h2f(q[j].y); a2 = fmaf(w, t.x, a2); a3 = fmaf(w, t.y, a3);
    }
  }
  const float4* Bq = (const float4*)bias;
  float4 b = Bq[fl];
  float4 o = make_float4(a0 + b.x, a1 + b.y, a2 + b.z, a3 + b.w);
  ((float4*)(Out + (size_t)v * 64))[fl] = o;
}

extern "C" void kernel_launch(void* const* d_in, const int* in_sizes, int n_in,
                              void* d_out, int out_size, void* d_ws, size_t ws_size,
                              hipStream_t stream) {
  const float* x  = (const float*)d_in[0];
  const int*   ei = (const int*)d_in[1];    // [2, E] row-major
  const int*   row = ei;                    // edge_index[0] (source)
  const int*   col = ei + Ne;               // edge_index[1] (dest / segment)
  const float* W1 = (const float*)d_in[2];
  const float* b1 = (const float*)d_in[3];
  const float* W2 = (const float*)d_in[4];
  const float* b2 = (const float*)d_in[5];
  float* out = (float*)d_out;

  char* ws = (char*)d_ws;
  size_t off = 0;
  auto alloc = [&](size_t bytes) -> void* {
    void* p = ws + off;
    off += (bytes + 255) & ~(size_t)255;
    return p;
  };
  int*    degi   = (int*)   alloc(Nn * sizeof(int));       // zeroed
  int*    rowptr = (int*)   alloc((Nn + 1) * sizeof(int));
  float*  dis    = (float*) alloc(Nn * sizeof(float));
  int*    bsum   = (int*)   alloc(64 * sizeof(int));
  unsigned short* rank = (unsigned short*)alloc((size_t)Ne * sizeof(unsigned short)); // 1.6 MB
  unsigned short* csr  = (unsigned short*)alloc((size_t)Ne * sizeof(unsigned short)); // 1.6 MB
  __half* H1     = (__half*)alloc((size_t)Nn * 128 * sizeof(__half));  // 12.8 MB
  __half* H2     = (__half*)alloc((size_t)Nn * 64 * sizeof(__half));   // 6.4 MB

  hipMemsetAsync(degi, 0, Nn * sizeof(int), stream);

  const int E2B = (Ne / 2 + 255) / 256;     // 1563 (2 edges/thread)
  const int NGB = (Nn + 15) / 16;           // 3125 node groups (16 nodes each)
  const int GT  = (Nn + 63) / 64;           // 782 node tiles (gemm)

  k_count<<<E2B, 256, 0, stream>>>((const int2*)col, degi, (ushort2*)rank);
  k_scan1<<<SCAN_B, 1024, 0, stream>>>(degi, rowptr, dis, bsum);
  k_scan3<<<SCAN_B, 1024, 0, stream>>>(rowptr, bsum);
  k_fill<<<E2B, 256, 0, stream>>>((const int2*)row, (const int2*)col, rowptr,
                                  (const ushort2*)rank, csr);

  // layer 1 GEMM: H1 = fp16(x @ W1)
  k_gemm_mfma<128><<<GT, 256, 0, stream>>>(x, W1, H1, Nn);
  // fused: H2 = fp16( relu(agg(H1) + b1) @ W2 )
  k_agg128_gemm64<<<NGB, 256, 0, stream>>>(H1, csr, rowptr, dis, b1, W2, H2, Nn);
  // layer 2 agg: out = agg(H2) + b2
  k_agg64<<<NGB, 256, 0, stream>>>(H2, csr, rowptr, dis, b2, out, Nn);
}